// Round 5
// baseline (450.443 us; speedup 1.0000x reference)
//
#include <hip/hip_runtime.h>

// ---------------------------------------------------------------------------
// LIIF forward, MI355X.  ALL tensors are float32 (per reference source).
// R21: liif_main REWRITTEN register-resident / barrier-free.
//   R20 banked 267.0us (liif 134.5 = R16 signature restored; gmat M-split
//   only -1.4us -> non-liif ~132us not gmat-makespan-bound).
//   liif diagnosis: 44% idle = s_h LDS round-trips (2.9M ds_read_b128,
//   4-way conflicts = the 4.37M conflict cycles) + 18 barriers/block
//   lockstep.  New decomposition: wave owns 32 rows (offset wv x 32
//   queries) end-to-end, loops all 8 M-tiles; activations stay in
//   registers across layers; C->B hand-off in-register via cvt_pkrtz +
//   __shfl_xor(32) (index algebra verified for all hi/g cases: C lane
//   (n,hi) holds m=8g+4hi+i; B lane(n,hi) needs k=16kb+8hi+j; one
//   lane^32 exchange per packed pair).  Barriers: 1 (bias/area staged) +
//   1 (blend).  s_h deleted; LDS ~7KB.  Weights per-wave-private: 4x L2
//   traffic (~1.4GB, ~16TB/s at target dur < 34.5 ceiling, XCD-cached).
//   MFMA total unchanged (8mt x 1nt == 2mt x 4nt per wave-layer).
//   L4 via same 32x32x16 path, wp4 padded to 32 out-ch (prep change).
// Prediction: liif 134 -> 60-85us (MfmaUtil 50-70, LDS ~7KB, conflicts
// <1M, VGPR 240-256, WRITE ~0.7MB, FETCH ~unchanged); total ~200-220.
// Tripwires: WRITE>2MB => spill => M-half passes next; absmax>5.86e-3 =>
// pack/shfl bug => revert R20; good counters but dur>=120 => A-frag
// latency-bound => LDS-stage weights per half-layer.
// ---------------------------------------------------------------------------

typedef _Float16 half8   __attribute__((ext_vector_type(8)));
typedef _Float16 half2v  __attribute__((ext_vector_type(2)));
typedef float    float4v __attribute__((ext_vector_type(4)));
typedef float    floatx16 __attribute__((ext_vector_type(16)));
typedef unsigned uint4v  __attribute__((ext_vector_type(4)));

// clamped f32->f16 (prep/conv/meta side)
__device__ __forceinline__ _Float16 to_h(float v) {
  return (_Float16)fminf(fmaxf(v, -60000.0f), 60000.0f);
}

#define NQ 30000
#define QT32 938   // ceil(NQ/32) tiles per batch
#define QTP32 940  // padded to 4-multiple; grid = 8*(QTP32/4) = 1880

// ---------------- weight repack (coalesced) --------------------------------
// wp layout: [kb2][n][8] f16, element (n, k=kb2*8+i) at ((kb2*N + n)*8 + i).
// wp0: N=256, kb2 0..73 (k 0..591, rows>=580 zero).  wp1..3: N=256, kb2 0..31.
// wp4 (R21): N=32 (out-ch padded 3->32), kb2 0..31.
__global__ void prep_kernel(const float* __restrict__ w0,
                            const float* __restrict__ w1,
                            const float* __restrict__ w2,
                            const float* __restrict__ w3,
                            const float* __restrict__ w4,
                            _Float16* __restrict__ p0, _Float16* __restrict__ p1,
                            _Float16* __restrict__ p2, _Float16* __restrict__ p3,
                            _Float16* __restrict__ p4) {
  int idx = blockIdx.x * 256 + threadIdx.x;
  if (idx < 18944) {                       // wp0: (kb,n), kb 0..73
    int kb = idx >> 8, n = idx & 255;
    half8 hv;
#pragma unroll
    for (int i = 0; i < 8; ++i) {
      int f = kb * 8 + i;                  // permuted feature index
      float v = 0.0f;
      if (f < 576)      v = w0[((f & 63) * 9 + (f >> 6)) * 256 + n];
      else if (f < 580) v = w0[f * 256 + n];
      hv[i] = (_Float16)v;
    }
    *(half8*)(p0 + idx * 8) = hv;
  } else if (idx < 43520) {                // wp1..3: l*(32kb*256n)
    int j = idx - 18944;
    int l = j >> 13;                       // 8192 = 32*256 per layer
    int j2 = j & 8191;
    int kb = j2 >> 8, n = j2 & 255;
    const float* w = (l == 0) ? w1 : (l == 1) ? w2 : w3;
    _Float16* p = (l == 0) ? p1 : (l == 1) ? p2 : p3;
    half8 hv;
#pragma unroll
    for (int i = 0; i < 8; ++i)
      hv[i] = (_Float16)w[(kb * 8 + i) * 256 + n];
    *(half8*)(p + j2 * 8) = hv;
  } else if (idx < 44544) {                // wp4: 32 kb2 x 32 n (padded)
    int j = idx - 43520;                   // 0..1023
    int kb2 = j >> 5, n = j & 31;
    half8 hv;
#pragma unroll
    for (int i = 0; i < 8; ++i) {
      int k = kb2 * 8 + i;
      float v = (n < 3) ? w4[k * 3 + n] : 0.0f;
      hv[i] = (_Float16)v;
    }
    *(half8*)(p4 + j * 8) = hv;
  }
}

// ---------------- conv 3x3 (3->64) + bias + tanh, zero-padded borders ------
__global__ void conv_kernel(const float* __restrict__ inp,
                            const float* __restrict__ cw,
                            const float* __restrict__ cb,
                            _Float16* __restrict__ P) {
  __shared__ __align__(16) float s_w[1728];
  __shared__ __align__(16) float s_b[64];
  for (int i = threadIdx.x; i < 1728; i += 256) s_w[i] = cw[i];
  if (threadIdx.x < 64) s_b[threadIdx.x] = cb[threadIdx.x];
  __syncthreads();
  int tid = blockIdx.x * 256 + threadIdx.x;
  if (tid >= 2 * 98 * 98) return;
  int b = tid / 9604;
  int rem = tid % 9604;
  int yy = rem / 98, xx = rem % 98;
  alignas(16) _Float16 outv[64];
  if (yy == 0 || yy == 97 || xx == 0 || xx == 97) {
#pragma unroll
    for (int c = 0; c < 64; ++c) outv[c] = (_Float16)0.0f;
  } else {
    int y = yy - 1, x = xx - 1;
    float win[27];
#pragma unroll
    for (int ci = 0; ci < 3; ++ci)
#pragma unroll
      for (int ky = 0; ky < 3; ++ky)
#pragma unroll
        for (int kx = 0; kx < 3; ++kx) {
          int yi = y + ky - 1, xi = x + kx - 1;
          float v = 0.0f;
          if (yi >= 0 && yi < 96 && xi >= 0 && xi < 96)
            v = inp[((b * 3 + ci) * 96 + yi) * 96 + xi];
          win[ci * 9 + ky * 3 + kx] = v;
        }
    for (int co = 0; co < 64; ++co) {
      float acc = s_b[co];
#pragma unroll
      for (int k = 0; k < 27; ++k) acc = fmaf(win[k], s_w[co * 27 + k], acc);
      outv[co] = (_Float16)tanhf(acc);
    }
  }
  _Float16* dst = P + tid * 64;
#pragma unroll
  for (int j = 0; j < 8; ++j) ((half8*)dst)[j] = ((const half8*)outv)[j];
}

// ---------------- G precompute (R20: M-split, 384 blocks) ------------------
// G[pix] = W0[0:576]^T * unfold(pix).  1 WG = 1 window-base row x 1 M-half.
__global__ __launch_bounds__(256, 2) void gmat_kernel(
    const _Float16* __restrict__ P,
    const _Float16* __restrict__ wp0,
    _Float16* __restrict__ G) {
  __shared__ __align__(16) _Float16 s_p[3][98][68];

  const int t    = threadIdx.x;
  const int lane = t & 63;
  const int wv   = t >> 6;
  const int ln32 = lane & 31;
  const int hi   = lane >> 5;
  const int blk  = blockIdx.x;
  const int bb   = (blk & 4) >> 2;               // batch, matches liif XCD rule
  const int mh   = (blk >> 3) & 1;               // M half (128 ch)
  const int y    = (blk >> 4) * 4 + (blk & 3);   // window-base row 0..95
  const int mt   = mh * 4 + wv;                  // global m-tile 0..7

  // ---- stage P rows y..y+2 (3 x 98 pixels x 64 ch) coalesced ----
  const int rowbase = (bb * 98 + y) * 98 * 64;   // element idx of row y
  for (int j = t; j < 2352; j += 256) {          // 2352 = 3*98*8 chunks
    int row = j / 784;                           // 784 = 98*8
    int jr  = j - row * 784;
    half8 v = *(const half8*)(P + rowbase + row * 6272 + jr * 8);
    *(half8*)(&s_p[row][jr >> 3][(jr & 7) * 8]) = v;
  }
  __syncthreads();

  // weight base for this wave's m-tile: n = mt*32 + ln32
  const _Float16* wb0 = wp0 + (hi * 256 + mt * 32 + ln32) * 8;

  floatx16 acc[3];
#pragma unroll
  for (int nt = 0; nt < 3; ++nt) acc[nt] = (floatx16)(0.0f);

  half8 afA, afB;
  afA = *(const half8*)(wb0);
  afB = *(const half8*)(wb0 + 4096);

#pragma unroll 1
  for (int s = 0; s < 36; s += 2) {
    // step s (A)
    {
      const int patch = s >> 2;
      const int py = patch / 3, px = patch % 3;
      const int cb = ((s & 3) << 4) + hi * 8;
      half8 bf[3];
#pragma unroll
      for (int nt = 0; nt < 3; ++nt)
        bf[nt] = *(const half8*)(&s_p[py][nt * 32 + ln32 + px][cb]);
#pragma unroll
      for (int nt = 0; nt < 3; ++nt)
        acc[nt] = __builtin_amdgcn_mfma_f32_32x32x16_f16(afA, bf[nt], acc[nt], 0, 0, 0);
      const int sp = (s + 2 <= 35) ? (s + 2) : 35;   // weight prefetch
      afA = *(const half8*)(wb0 + sp * 4096);
    }
    // step s+1 (B)
    {
      const int s1 = s + 1;
      const int patch = s1 >> 2;
      const int py = patch / 3, px = patch % 3;
      const int cb = ((s1 & 3) << 4) + hi * 8;
      half8 bf[3];
#pragma unroll
      for (int nt = 0; nt < 3; ++nt)
        bf[nt] = *(const half8*)(&s_p[py][nt * 32 + ln32 + px][cb]);
#pragma unroll
      for (int nt = 0; nt < 3; ++nt)
        acc[nt] = __builtin_amdgcn_mfma_f32_32x32x16_f16(afB, bf[nt], acc[nt], 0, 0, 0);
      const int sp = (s + 3 <= 35) ? (s + 3) : 35;
      afB = *(const half8*)(wb0 + sp * 4096);
    }
  }
  // permuted store (RNE cvt): regs 0..15 already in ch' order q*4+i
  const int gybase = ((bb * 98 + y) * 98) * 256;
#pragma unroll
  for (int nt = 0; nt < 3; ++nt) {
    half8 c0, c1;
#pragma unroll
    for (int j = 0; j < 8; ++j) {
      c0[j] = (_Float16)acc[nt][j];
      c1[j] = (_Float16)acc[nt][8 + j];
    }
    _Float16* ga = G + gybase + (nt * 32 + ln32) * 256 + mt * 32 + hi * 16;
    *(half8*)(ga)     = c0;
    *(half8*)(ga + 8) = c1;
  }
}

// ---------------- main: register-resident, barrier-free MLP ----------------
// Wave = (offset wv, 32 queries).  acc[8] = 256 out-ch x 32 rows.
// C/D layout (m74/m101): n=lane&31 (row), m=(reg&3)+8*(reg>>2)+4*(lane>>5).
// B-frag (32x32x16): lane(n,hi) holds k = kb*16 + hi*8 + j (j=0..7).

// acc (+bias, relu) -> packed B-frags for next layer, fully in-register.
__device__ __forceinline__ void pack_h(floatx16 (&acc)[8],
                                       const float* __restrict__ sb,
                                       int hi, unsigned (&hb)[16][4]) {
#pragma unroll
  for (int mt = 0; mt < 8; ++mt) {
    unsigned p0[4], p1[4];
#pragma unroll
    for (int g = 0; g < 4; ++g) {
      const int m0 = mt * 32 + 8 * g + 4 * hi;
      float b0 = sb[m0], b1 = sb[m0 + 1], b2 = sb[m0 + 2], b3 = sb[m0 + 3];
      float v0 = fmaxf(acc[mt][4 * g + 0] + b0, 0.0f);
      float v1 = fmaxf(acc[mt][4 * g + 1] + b1, 0.0f);
      float v2 = fmaxf(acc[mt][4 * g + 2] + b2, 0.0f);
      float v3 = fmaxf(acc[mt][4 * g + 3] + b3, 0.0f);
      p0[g] = __builtin_bit_cast(unsigned, __builtin_amdgcn_cvt_pkrtz(v0, v1));
      p1[g] = __builtin_bit_cast(unsigned, __builtin_amdgcn_cvt_pkrtz(v2, v3));
    }
    // exchange with partner lane (^32): send the pack the partner needs
    unsigned s00 = hi ? p0[0] : p0[1];
    unsigned s01 = hi ? p1[0] : p1[1];
    unsigned s10 = hi ? p0[2] : p0[3];
    unsigned s11 = hi ? p1[2] : p1[3];
    unsigned r00 = __shfl_xor(s00, 32);
    unsigned r01 = __shfl_xor(s01, 32);
    unsigned r10 = __shfl_xor(s10, 32);
    unsigned r11 = __shfl_xor(s11, 32);
    // verified index algebra (see header): B[2mt] from g={hi}, B[2mt+1] g={2+hi}
    hb[2 * mt][0]     = hi ? r00   : p0[0];
    hb[2 * mt][1]     = hi ? r01   : p1[0];
    hb[2 * mt][2]     = hi ? p0[1] : r00;
    hb[2 * mt][3]     = hi ? p1[1] : r01;
    hb[2 * mt + 1][0] = hi ? r10   : p0[2];
    hb[2 * mt + 1][1] = hi ? r11   : p1[2];
    hb[2 * mt + 1][2] = hi ? p0[3] : r10;
    hb[2 * mt + 1][3] = hi ? p1[3] : r11;
  }
}

// K=256 layer: weights from L2 (per-wave), B from registers.
__device__ __forceinline__ void layerR(const _Float16* __restrict__ wbase,
                                       const unsigned (&hb)[16][4],
                                       floatx16 (&acc)[8]) {
#pragma unroll
  for (int mt = 0; mt < 8; ++mt) acc[mt] = (floatx16)(0.0f);
#pragma unroll
  for (int kb = 0; kb < 16; ++kb) {
    uint4v u = {hb[kb][0], hb[kb][1], hb[kb][2], hb[kb][3]};
    half8 bf = __builtin_bit_cast(half8, u);
#pragma unroll
    for (int mt = 0; mt < 8; ++mt) {
      half8 af = *(const half8*)(wbase + kb * 4096 + mt * 256);
      acc[mt] = __builtin_amdgcn_mfma_f32_32x32x16_f16(af, bf, acc[mt], 0, 0, 0);
    }
  }
}

__global__ __launch_bounds__(256, 2) void liif_main(
    const float* __restrict__ coord, const float* __restrict__ cell,
    const float* __restrict__ bias0, const float* __restrict__ bias1,
    const float* __restrict__ bias2, const float* __restrict__ bias3,
    const float* __restrict__ bias4,
    const _Float16* __restrict__ G,
    const _Float16* __restrict__ wp0, const _Float16* __restrict__ wp1,
    const _Float16* __restrict__ wp2, const _Float16* __restrict__ wp3,
    const _Float16* __restrict__ wp4,
    float* __restrict__ out) {
  __shared__ __align__(16) float s_bias[1028];
  __shared__ __align__(16) float s_area[4][32];
  __shared__ __align__(16) float s_o4[4][32][4];

  const int t    = threadIdx.x;
  const int lane = t & 63;
  const int wv   = t >> 6;        // offset o = wv
  const int ln32 = lane & 31;     // query row within tile
  const int hi   = lane >> 5;
  const int blk  = blockIdx.x;
  const int bb   = (blk & 4) >> 2;             // batch = bit2 -> stable per XCD
  const int tile = (blk >> 3) * 4 + (blk & 3); // 0..939
  const int q0   = tile * 32;

  // ---- stage biases into LDS (1027 f32) ----
  for (int i = t; i < 1027; i += 256) {
    float v;
    if (i < 256)       v = bias0[i];
    else if (i < 512)  v = bias1[i - 256];
    else if (i < 768)  v = bias2[i - 512];
    else if (i < 1024) v = bias3[i - 768];
    else               v = bias4[i - 1024];
    s_bias[i] = v;
  }

  // ---- per-lane meta (both hi halves duplicate; hi==0 writes area) ----
  const int q = q0 + ln32;
  const bool valid = q < NQ;
  float c0 = 0.f, c1 = 0.f, e0 = 0.f, e1 = 0.f;
  if (valid) {
    int base = (bb * NQ + q) * 2;
    c0 = coord[base]; c1 = coord[base + 1];
    e0 = cell[base];  e1 = cell[base + 1];
  }
  const float rc0 = e0 * 96.0f, rc1 = e1 * 96.0f;
  const float oy = (wv < 2) ? -1.0f : 1.0f;    // offsets [-1,-1],[-1,1],[1,-1],[1,1]
  const float ox = (wv & 1) ? 1.0f : -1.0f;
  float ec0 = (c0 + oy * (1.0f / 96.0f)) + 1e-6f;
  float ec1 = (c1 + ox * (1.0f / 96.0f)) + 1e-6f;
  ec0 = fminf(fmaxf(ec0, -1.0f), 1.0f);        // f32(-1+1e-10) == -1.0f
  ec1 = fminf(fmaxf(ec1, -1.0f), 1.0f);
  int iy = (int)rintf(((ec0 + 1.0f) * 96.0f) * 0.5f - 0.5f);  // half-even
  int ix = (int)rintf(((ec1 + 1.0f) * 96.0f) * 0.5f - 0.5f);
  iy = min(max(iy, 0), 95); ix = min(max(ix, 0), 95);
  const float qc0 = -1.0f + (2.0f * (float)iy + 1.0f) / 96.0f;
  const float qc1 = -1.0f + (2.0f * (float)ix + 1.0f) / 96.0f;
  const float r0 = (c0 - qc0) * 96.0f;
  const float r1 = (c1 - qc1) * 96.0f;
  const int   pix = (bb * 98 + iy) * 98 + ix;  // padded pixel base
  if (hi == 0) s_area[wv][ln32] = fabsf(r0 * r1) + 1e-9f;
  __syncthreads();   // bias + areas ready; no more barriers until blend

  // ---------------- layer 0: acc init from G + one ext K=16 step ----------
  floatx16 acc[8];
#pragma unroll
  for (int mt = 0; mt < 8; ++mt) {
    const _Float16* ga = G + pix * 256 + mt * 32 + hi * 16;
    half8 g0 = *(const half8*)(ga);
    half8 g1 = *(const half8*)(ga + 8);
    floatx16 a;
#pragma unroll
    for (int j = 0; j < 8; ++j) {
      a[j]     = (float)g0[j];
      a[8 + j] = (float)g1[j];
    }
    acc[mt] = a;
  }
  {  // ext step (kb2 72+hi): W0 rows 576..591 (rows >= 580 are zero)
    half8 bfe = {(_Float16)0, (_Float16)0, (_Float16)0, (_Float16)0,
                 (_Float16)0, (_Float16)0, (_Float16)0, (_Float16)0};
    if (hi == 0) {
      bfe[0] = to_h(r0); bfe[1] = to_h(r1); bfe[2] = to_h(rc0); bfe[3] = to_h(rc1);
    }
    const _Float16* we = wp0 + 36 * 4096 + (hi * 256 + ln32) * 8;
#pragma unroll
    for (int mt = 0; mt < 8; ++mt) {
      half8 ae = *(const half8*)(we + mt * 256);
      acc[mt] = __builtin_amdgcn_mfma_f32_32x32x16_f16(ae, bfe, acc[mt], 0, 0, 0);
    }
  }

  unsigned hb[16][4];
  pack_h(acc, s_bias, hi, hb);                 // h1  (bias0 + relu)

  const _Float16* wbase1 = wp1 + (hi * 256 + ln32) * 8;
  const _Float16* wbase2 = wp2 + (hi * 256 + ln32) * 8;
  const _Float16* wbase3 = wp3 + (hi * 256 + ln32) * 8;

  layerR(wbase1, hb, acc);
  pack_h(acc, s_bias + 256, hi, hb);           // h2
  layerR(wbase2, hb, acc);
  pack_h(acc, s_bias + 512, hi, hb);           // h3
  layerR(wbase3, hb, acc);
  pack_h(acc, s_bias + 768, hi, hb);           // h4

  // ---------------- layer 4: 256 -> 3 (out-ch padded to 32) ---------------
  floatx16 a4 = (floatx16)(0.0f);
  {
    const _Float16* w4base = wp4 + (hi * 32 + ln32) * 8;   // (kb2= hi within kstep)
#pragma unroll
    for (int kb = 0; kb < 16; ++kb) {
      uint4v u = {hb[kb][0], hb[kb][1], hb[kb][2], hb[kb][3]};
      half8 bf = __builtin_bit_cast(half8, u);
      half8 af = *(const half8*)(w4base + kb * 512);       // ((2kb+hi)*32+n)*8
      a4 = __builtin_amdgcn_mfma_f32_32x32x16_f16(af, bf, a4, 0, 0, 0);
    }
  }
  // out-ch 0..2 live in regs 0..2 of hi==0 lanes (m = 8g+4hi+i)
  if (hi == 0) {
    s_o4[wv][ln32][0] = a4[0];
    s_o4[wv][ln32][1] = a4[1];
    s_o4[wv][ln32][2] = a4[2];
  }
  __syncthreads();                 // blend barrier

  // ---- final: out = tanh(num/den + b4) * 1.01, f32 (areas reversed) ----
  if (t < 32) {
    int qq = q0 + t;
    if (qq < NQ) {
      float a0 = s_area[0][t], a1 = s_area[1][t], a2 = s_area[2][t], a3 = s_area[3][t];
      float den = a0 + a1 + a2 + a3;
      int ob = (bb * NQ + qq) * 3;
#pragma unroll
      for (int j = 0; j < 3; ++j) {
        float num = s_o4[0][t][j] * a3 + s_o4[1][t][j] * a2 +
                    s_o4[2][t][j] * a1 + s_o4[3][t][j] * a0;
        float v = num / den + s_bias[1024 + j];
        out[ob + j] = tanhf(v) * 1.01f;
      }
    }
  }
}

// ---------------------------------------------------------------------------
extern "C" void kernel_launch(void* const* d_in, const int* in_sizes, int n_in,
                              void* d_out, int out_size, void* d_ws, size_t ws_size,
                              hipStream_t stream) {
  const float* inp   = (const float*)d_in[0];
  const float* coord = (const float*)d_in[1];
  const float* cell  = (const float*)d_in[2];
  const float* cw    = (const float*)d_in[3];
  const float* cb    = (const float*)d_in[4];
  const float* w0    = (const float*)d_in[5];
  const float* b0    = (const float*)d_in[6];
  const float* w1    = (const float*)d_in[7];
  const float* b1    = (const float*)d_in[8];
  const float* w2    = (const float*)d_in[9];
  const float* b2    = (const float*)d_in[10];
  const float* w3    = (const float*)d_in[11];
  const float* b3    = (const float*)d_in[12];
  const float* w4    = (const float*)d_in[13];
  const float* b4    = (const float*)d_in[14];

  char* ws = (char*)d_ws;
  _Float16* P   = (_Float16*)(ws);            // 2,458,624 B
  _Float16* wp0 = (_Float16*)(ws + 2458624);  //   303,104 B (74 kb)
  _Float16* wp1 = (_Float16*)(ws + 2761728);  //   131,072 B
  _Float16* wp2 = (_Float16*)(ws + 2892800);
  _Float16* wp3 = (_Float16*)(ws + 3023872);
  _Float16* wp4 = (_Float16*)(ws + 3154944);  //    16,384 B (32kb2 x 32n, R21)
  _Float16* G   = (_Float16*)(ws + 3171328);  // 9,834,496 B (2*98*98*256 f16)
  float* outp = (float*)d_out;

  hipLaunchKernelGGL(prep_kernel, dim3(174), dim3(256), 0, stream,
                     w0, w1, w2, w3, w4, wp0, wp1, wp2, wp3, wp4);
  hipLaunchKernelGGL(conv_kernel, dim3(76), dim3(256), 0, stream, inp, cw, cb, P);
  hipLaunchKernelGGL(gmat_kernel, dim3(384), dim3(256), 0, stream, P, wp0, G);
  hipLaunchKernelGGL(liif_main, dim3(8 * (QTP32 / 4)), dim3(256), 0, stream,
                     coord, cell, b0, b1, b2, b3, b4,
                     G, wp0, wp1, wp2, wp3, wp4, outp);
}

// Round 6
// 324.384 us; speedup vs baseline: 1.3886x; 1.3886x over previous
//
#include <hip/hip_runtime.h>

// ---------------------------------------------------------------------------
// LIIF forward, MI355X.  ALL tensors are float32 (per reference source).
// R22 = R20 + (a) prep+conv FUSED into one 248-block kernel (they are
// independent; sum -> max + one launch gap saved) + (b) liif pass-1 G-gather
// PREFETCH (T14): issue the 16x16B loads after pass-0's L3-writeback sync,
// consume at pass-1 acc-init; latency hides under L4+blend.  acc regs are
// dead at the prefetch point so peak pressure doesn't rise.
//   R21 post-mortem (liif 316us, MfmaUtil 12.8, VALUBusy 9.9, absmax OK,
//   no spill): per-wave-private weights made every MFMA's A-frag a fresh
//   dependent L2 load (R16 reused each A-frag x4 across n-tiles) -> L2
//   latency chain at 2 waves/SIMD.  Lesson: A-operand reuse across n-tiles
//   is what makes R16's inner loop self-hiding.
//   liif structural status: 134us = verified local optimum of R16 structure
//   (MfmaUtil 31% == arithmetic floor ratio exactly; 4 escape attempts all
//   regressed for understood reasons).
// Prediction: liif -> 130-133 (VGPR 120-150, WRITE ~0.7MB; >2MB => prefetch
// spilled => revert prefetch), 3 dispatches, total -> 255-262.  If >=265
// with R16-signature liif counters => remainder is harness floor => declare.
// R12 recap: G[pixel] = W0[0:576]^T unfold(pixel) in MFMA C-layout order
// (ch' = mt*32+hi*16+q*4+i <-> m = 8q+4hi+i); liif L0 = G gather (acc init)
// + one K=16 ext MFMA step; layers 1-3 32x32x16 ping-pong, packed cvt
// writeback, post-barrier weight loads.  absmax > 5.86e-3 => bug.
// ---------------------------------------------------------------------------

typedef _Float16 half8   __attribute__((ext_vector_type(8)));
typedef _Float16 half4v  __attribute__((ext_vector_type(4)));
typedef _Float16 half2v  __attribute__((ext_vector_type(2)));
typedef float    float4v __attribute__((ext_vector_type(4)));
typedef float    floatx16 __attribute__((ext_vector_type(16)));

// clamped f32->f16 (prep/conv side only)
__device__ __forceinline__ _Float16 to_h(float v) {
  return (_Float16)fminf(fmaxf(v, -60000.0f), 60000.0f);
}

#define NQ 30000
#define QT 469   // ceil(NQ/64) real tiles per batch
#define QTP 472  // padded to 4-multiple for XCD-partitioned grid (944 blocks)

// ---------------- fused weight repack + conv (R22) -------------------------
// blocks 0..75: conv 3x3 (3->64) + bias + tanh (19208 padded pixels)
// blocks 76..247: weight repack (idx < 44032), R14 layout:
//   wp: [kb][n][8] f16, element (n, k=kb*8+i) at ((kb*N + n)*8 + i).
__global__ void prep_conv_kernel(const float* __restrict__ w0,
                                 const float* __restrict__ w1,
                                 const float* __restrict__ w2,
                                 const float* __restrict__ w3,
                                 const float* __restrict__ w4,
                                 _Float16* __restrict__ p0, _Float16* __restrict__ p1,
                                 _Float16* __restrict__ p2, _Float16* __restrict__ p3,
                                 _Float16* __restrict__ p4,
                                 const float* __restrict__ inp,
                                 const float* __restrict__ cw,
                                 const float* __restrict__ cb,
                                 _Float16* __restrict__ P) {
  __shared__ __align__(16) float s_w[1728];
  __shared__ __align__(16) float s_b[64];
  if (blockIdx.x < 76) {
    // ---------------- conv part ----------------
    for (int i = threadIdx.x; i < 1728; i += 256) s_w[i] = cw[i];
    if (threadIdx.x < 64) s_b[threadIdx.x] = cb[threadIdx.x];
    __syncthreads();
    int tid = blockIdx.x * 256 + threadIdx.x;
    if (tid >= 2 * 98 * 98) return;
    int b = tid / 9604;
    int rem = tid % 9604;
    int yy = rem / 98, xx = rem % 98;
    alignas(16) _Float16 outv[64];
    if (yy == 0 || yy == 97 || xx == 0 || xx == 97) {
#pragma unroll
      for (int c = 0; c < 64; ++c) outv[c] = (_Float16)0.0f;
    } else {
      int y = yy - 1, x = xx - 1;
      float win[27];
#pragma unroll
      for (int ci = 0; ci < 3; ++ci)
#pragma unroll
        for (int ky = 0; ky < 3; ++ky)
#pragma unroll
          for (int kx = 0; kx < 3; ++kx) {
            int yi = y + ky - 1, xi = x + kx - 1;
            float v = 0.0f;
            if (yi >= 0 && yi < 96 && xi >= 0 && xi < 96)
              v = inp[((b * 3 + ci) * 96 + yi) * 96 + xi];
            win[ci * 9 + ky * 3 + kx] = v;
          }
      for (int co = 0; co < 64; ++co) {
        float acc = s_b[co];
#pragma unroll
        for (int k = 0; k < 27; ++k) acc = fmaf(win[k], s_w[co * 27 + k], acc);
        outv[co] = (_Float16)tanhf(acc);
      }
    }
    _Float16* dst = P + tid * 64;
#pragma unroll
    for (int j = 0; j < 8; ++j) ((half8*)dst)[j] = ((const half8*)outv)[j];
  } else {
    // ---------------- prep part ----------------
    int idx = (blockIdx.x - 76) * 256 + threadIdx.x;
    if (idx < 18944) {                       // wp0: (kb,n), kb 0..73
      int kb = idx >> 8, n = idx & 255;
      half8 hv;
#pragma unroll
      for (int i = 0; i < 8; ++i) {
        int f = kb * 8 + i;                  // permuted feature index
        float v = 0.0f;
        if (f < 576)      v = w0[((f & 63) * 9 + (f >> 6)) * 256 + n];
        else if (f < 580) v = w0[f * 256 + n];
        hv[i] = (_Float16)v;
      }
      *(half8*)(p0 + idx * 8) = hv;
    } else if (idx < 43520) {                // wp1..3: l*(32kb*256n)
      int j = idx - 18944;
      int l = j >> 13;                       // 8192 = 32*256 per layer
      int j2 = j & 8191;
      int kb = j2 >> 8, n = j2 & 255;
      const float* w = (l == 0) ? w1 : (l == 1) ? w2 : w3;
      _Float16* p = (l == 0) ? p1 : (l == 1) ? p2 : p3;
      half8 hv;
#pragma unroll
      for (int i = 0; i < 8; ++i)
        hv[i] = (_Float16)w[(kb * 8 + i) * 256 + n];
      *(half8*)(p + j2 * 8) = hv;
    } else if (idx < 44032) {                // wp4: 32kb * 16n
      int j = idx - 43520;
      int kb = j >> 4, n = j & 15;
      half8 hv;
#pragma unroll
      for (int i = 0; i < 8; ++i) {
        float v = (n < 3) ? w4[(kb * 8 + i) * 3 + n] : 0.0f;
        hv[i] = (_Float16)v;
      }
      *(half8*)(p4 + j * 8) = hv;
    }
  }
}

// ---------------- G precompute (R20: M-split, 384 blocks) ------------------
// G[pix] = W0[0:576]^T * unfold(pix).  1 WG = 1 window-base row x 1 M-half.
// Grid 384: bb = bit2 (same XCD rule as liif), mh = bit3, y = (blk>>4)*4 +
// (blk&3).  4 waves x 1 m-tile (32 ch) each: global m-tile = mh*4 + wv.
// LDS s_p[3][98][68]: pixel stride 68 halves = 34 dw = 2 mod 32 -> <=2-way
// bank conflicts (free).  acc[3]; store pre-permuted (R12 layout).
__global__ __launch_bounds__(256, 2) void gmat_kernel(
    const _Float16* __restrict__ P,
    const _Float16* __restrict__ wp0,
    _Float16* __restrict__ G) {
  __shared__ __align__(16) _Float16 s_p[3][98][68];

  const int t    = threadIdx.x;
  const int lane = t & 63;
  const int wv   = t >> 6;
  const int ln32 = lane & 31;
  const int hi   = lane >> 5;
  const int blk  = blockIdx.x;
  const int bb   = (blk & 4) >> 2;               // batch, matches liif XCD rule
  const int mh   = (blk >> 3) & 1;               // M half (128 ch)
  const int y    = (blk >> 4) * 4 + (blk & 3);   // window-base row 0..95
  const int mt   = mh * 4 + wv;                  // global m-tile 0..7

  // ---- stage P rows y..y+2 (3 x 98 pixels x 64 ch) coalesced ----
  const int rowbase = (bb * 98 + y) * 98 * 64;   // element idx of row y
  for (int j = t; j < 2352; j += 256) {          // 2352 = 3*98*8 chunks
    int row = j / 784;                           // 784 = 98*8
    int jr  = j - row * 784;
    half8 v = *(const half8*)(P + rowbase + row * 6272 + jr * 8);
    *(half8*)(&s_p[row][jr >> 3][(jr & 7) * 8]) = v;
  }
  __syncthreads();

  // weight base for this wave's m-tile: n = mt*32 + ln32
  const _Float16* wb0 = wp0 + (hi * 256 + mt * 32 + ln32) * 8;

  floatx16 acc[3];
#pragma unroll
  for (int nt = 0; nt < 3; ++nt) acc[nt] = (floatx16)(0.0f);

  half8 afA, afB;
  afA = *(const half8*)(wb0);
  afB = *(const half8*)(wb0 + 4096);

#pragma unroll 1
  for (int s = 0; s < 36; s += 2) {
    // step s (A)
    {
      const int patch = s >> 2;
      const int py = patch / 3, px = patch % 3;
      const int cb = ((s & 3) << 4) + hi * 8;
      half8 bf[3];
#pragma unroll
      for (int nt = 0; nt < 3; ++nt)
        bf[nt] = *(const half8*)(&s_p[py][nt * 32 + ln32 + px][cb]);
#pragma unroll
      for (int nt = 0; nt < 3; ++nt)
        acc[nt] = __builtin_amdgcn_mfma_f32_32x32x16_f16(afA, bf[nt], acc[nt], 0, 0, 0);
      const int sp = (s + 2 <= 35) ? (s + 2) : 35;   // weight prefetch
      afA = *(const half8*)(wb0 + sp * 4096);
    }
    // step s+1 (B)
    {
      const int s1 = s + 1;
      const int patch = s1 >> 2;
      const int py = patch / 3, px = patch % 3;
      const int cb = ((s1 & 3) << 4) + hi * 8;
      half8 bf[3];
#pragma unroll
      for (int nt = 0; nt < 3; ++nt)
        bf[nt] = *(const half8*)(&s_p[py][nt * 32 + ln32 + px][cb]);
#pragma unroll
      for (int nt = 0; nt < 3; ++nt)
        acc[nt] = __builtin_amdgcn_mfma_f32_32x32x16_f16(afB, bf[nt], acc[nt], 0, 0, 0);
      const int sp = (s + 3 <= 35) ? (s + 3) : 35;
      afB = *(const half8*)(wb0 + sp * 4096);
    }
  }
  // permuted store (RNE cvt): regs 0..15 already in ch' order q*4+i
  const int gybase = ((bb * 98 + y) * 98) * 256;
#pragma unroll
  for (int nt = 0; nt < 3; ++nt) {
    half8 c0, c1;
#pragma unroll
    for (int j = 0; j < 8; ++j) {
      c0[j] = (_Float16)acc[nt][j];
      c1[j] = (_Float16)acc[nt][8 + j];
    }
    _Float16* ga = G + gybase + (nt * 32 + ln32) * 256 + mt * 32 + hi * 16;
    *(half8*)(ga)     = c0;
    *(half8*)(ga + 8) = c1;
  }
}

// ---------------- main: gather + MLP + blend (R16 + T14 prefetch) ----------
// WG = 256 thr = 4 waves = 64 queries x 2 offsets (128 rows) per pass.
// 32x32x16 C/D (measured m74/m101): n=lane&31, m=(reg&3)+8*(reg>>2)+4*(lane>>5).
__device__ __forceinline__ void writeback32(floatx16 (&acc)[2][4],
                                            const float* __restrict__ sb,
                                            _Float16 (*s_h)[264],
                                            int wv, int ln32, int hi) {
#pragma unroll
  for (int mt2 = 0; mt2 < 2; ++mt2) {
    const int mb = wv * 64 + mt2 * 32 + 4 * hi;
#pragma unroll
    for (int g = 0; g < 4; ++g) {
      const int m0 = mb + 8 * g;
      float b0 = sb[m0], b1 = sb[m0 + 1], b2 = sb[m0 + 2], b3 = sb[m0 + 3];
#pragma unroll
      for (int nt2 = 0; nt2 < 4; ++nt2) {
        const int n = nt2 * 32 + ln32;
        float v0 = fmaxf(acc[mt2][nt2][4 * g + 0] + b0, 0.0f);
        float v1 = fmaxf(acc[mt2][nt2][4 * g + 1] + b1, 0.0f);
        float v2 = fmaxf(acc[mt2][nt2][4 * g + 2] + b2, 0.0f);
        float v3 = fmaxf(acc[mt2][nt2][4 * g + 3] + b3, 0.0f);
        half2v lo  = __builtin_bit_cast(half2v, __builtin_amdgcn_cvt_pkrtz(v0, v1));
        half2v hi2 = __builtin_bit_cast(half2v, __builtin_amdgcn_cvt_pkrtz(v2, v3));
        half4v hv;
        hv[0] = lo[0]; hv[1] = lo[1]; hv[2] = hi2[0]; hv[3] = hi2[1];
        *(half4v*)(&s_h[n][m0]) = hv;
      }
    }
  }
}

// K=256 layer from s_h, ping-pong pipelined; loads after caller's barrier.
__device__ __forceinline__ void layer256(const _Float16* __restrict__ wbl,
                                         _Float16 (*s_h)[264],
                                         int ln32, int hi,
                                         floatx16 (&acc)[2][4]) {
#pragma unroll
  for (int mt2 = 0; mt2 < 2; ++mt2)
#pragma unroll
    for (int nt2 = 0; nt2 < 4; ++nt2) acc[mt2][nt2] = (floatx16)(0.0f);
  half8 afA[2], afB[2], bfA[4], bfB[4];
  afA[0] = *(const half8*)(wbl);
  afA[1] = *(const half8*)(wbl + 256);
  afB[0] = *(const half8*)(wbl + 4096);
  afB[1] = *(const half8*)(wbl + 4096 + 256);
#pragma unroll
  for (int nt2 = 0; nt2 < 4; ++nt2) {
    bfA[nt2] = *(const half8*)(&s_h[nt2 * 32 + ln32][hi * 8]);
    bfB[nt2] = *(const half8*)(&s_h[nt2 * 32 + ln32][16 + hi * 8]);
  }
#pragma unroll 1
  for (int s = 0; s < 16; s += 2) {
#pragma unroll
    for (int mt2 = 0; mt2 < 2; ++mt2)
#pragma unroll
      for (int nt2 = 0; nt2 < 4; ++nt2)
        acc[mt2][nt2] = __builtin_amdgcn_mfma_f32_32x32x16_f16(
            afA[mt2], bfA[nt2], acc[mt2][nt2], 0, 0, 0);
    {
      const int sc = (s + 2 < 16) ? (s + 2) : 0;
      const int sw = (s + 2 < 16) ? (s + 2) : 15;
      afA[0] = *(const half8*)(wbl + sw * 4096);
      afA[1] = *(const half8*)(wbl + sw * 4096 + 256);
#pragma unroll
      for (int nt2 = 0; nt2 < 4; ++nt2)
        bfA[nt2] = *(const half8*)(&s_h[nt2 * 32 + ln32][sc * 16 + hi * 8]);
    }
#pragma unroll
    for (int mt2 = 0; mt2 < 2; ++mt2)
#pragma unroll
      for (int nt2 = 0; nt2 < 4; ++nt2)
        acc[mt2][nt2] = __builtin_amdgcn_mfma_f32_32x32x16_f16(
            afB[mt2], bfB[nt2], acc[mt2][nt2], 0, 0, 0);
    {
      const int sc = (s + 3 < 16) ? (s + 3) : 0;
      const int sw = (s + 3 < 16) ? (s + 3) : 15;
      afB[0] = *(const half8*)(wbl + sw * 4096);
      afB[1] = *(const half8*)(wbl + sw * 4096 + 256);
#pragma unroll
      for (int nt2 = 0; nt2 < 4; ++nt2)
        bfB[nt2] = *(const half8*)(&s_h[nt2 * 32 + ln32][sc * 16 + hi * 8]);
    }
  }
}

__global__ __launch_bounds__(256, 2) void liif_main(
    const float* __restrict__ coord, const float* __restrict__ cell,
    const float* __restrict__ bias0, const float* __restrict__ bias1,
    const float* __restrict__ bias2, const float* __restrict__ bias3,
    const float* __restrict__ bias4,
    const _Float16* __restrict__ G,
    const _Float16* __restrict__ wp0, const _Float16* __restrict__ wp1,
    const _Float16* __restrict__ wp2, const _Float16* __restrict__ wp3,
    const _Float16* __restrict__ wp4,
    float* __restrict__ out) {
  __shared__ __align__(16) int      s_pix[4][64];
  __shared__ __align__(16) float    s_area[4][64];
  __shared__ __align__(16) _Float16 s_ext[4][64][8];
  __shared__ __align__(16) float    s_bias[1028];
  __shared__ __align__(16) float    s_out[128][4];
  __shared__ __align__(16) float    s_num[64][4];
  __shared__ __align__(16) _Float16 s_h[128][264]; // stride 132 dw = 4 mod 32

  const int t   = threadIdx.x;
  const int blk = blockIdx.x;
  const int bb  = (blk & 4) >> 2;            // batch = bit2 -> stable per XCD
  const int tile = (blk >> 3) * 4 + (blk & 3);
  const int q0  = tile * 64;

  // ---- stage biases into LDS (1027 f32) ----
  for (int i = t; i < 1027; i += 256) {
    float v;
    if (i < 256)       v = bias0[i];
    else if (i < 512)  v = bias1[i - 256];
    else if (i < 768)  v = bias2[i - 512];
    else if (i < 1024) v = bias3[i - 768];
    else               v = bias4[i - 1024];
    s_bias[i] = v;
  }

  // ---- phase 0: per-row meta for all 4 offsets (f32, matches np) ----
  if (t < 64) {
    int q = q0 + t;
    bool valid = q < NQ;
    float c0 = 0.f, c1 = 0.f, e0 = 0.f, e1 = 0.f;
    if (valid) {
      int base = (bb * NQ + q) * 2;
      c0 = coord[base]; c1 = coord[base + 1];
      e0 = cell[base];  e1 = cell[base + 1];
    }
    float rc0 = e0 * 96.0f, rc1 = e1 * 96.0f;
#pragma unroll
    for (int o = 0; o < 4; ++o) {
      float oy = (o < 2) ? -1.0f : 1.0f;     // offsets [-1,-1],[-1,1],[1,-1],[1,1]
      float ox = (o & 1) ? 1.0f : -1.0f;
      float ec0 = (c0 + oy * (1.0f / 96.0f)) + 1e-6f;
      float ec1 = (c1 + ox * (1.0f / 96.0f)) + 1e-6f;
      ec0 = fminf(fmaxf(ec0, -1.0f), 1.0f);  // f32(-1+1e-10) == -1.0f
      ec1 = fminf(fmaxf(ec1, -1.0f), 1.0f);
      int iy = (int)rintf(((ec0 + 1.0f) * 96.0f) * 0.5f - 0.5f);  // half-even
      int ix = (int)rintf(((ec1 + 1.0f) * 96.0f) * 0.5f - 0.5f);
      iy = min(max(iy, 0), 95); ix = min(max(ix, 0), 95);
      float qc0 = -1.0f + (2.0f * (float)iy + 1.0f) / 96.0f;
      float qc1 = -1.0f + (2.0f * (float)ix + 1.0f) / 96.0f;
      float r0 = (c0 - qc0) * 96.0f;
      float r1 = (c1 - qc1) * 96.0f;
      s_pix[o][t]  = (bb * 98 + iy) * 98 + ix;   // padded pixel base
      s_area[o][t] = fabsf(r0 * r1) + 1e-9f;
      s_ext[o][t][0] = to_h(r0);  s_ext[o][t][1] = to_h(r1);
      s_ext[o][t][2] = to_h(rc0); s_ext[o][t][3] = to_h(rc1);
      s_ext[o][t][4] = (_Float16)0.0f; s_ext[o][t][5] = (_Float16)0.0f;
      s_ext[o][t][6] = (_Float16)0.0f; s_ext[o][t][7] = (_Float16)0.0f;
    }
    s_num[t][0] = 0.f; s_num[t][1] = 0.f; s_num[t][2] = 0.f; s_num[t][3] = 0.f;
  }
  __syncthreads();

  const int lane = t & 63;
  const int wv   = t >> 6;
  const int ln32 = lane & 31;
  const int hi   = lane >> 5;
  const int ln16 = lane & 15;
  const int lg   = lane >> 4;

  const _Float16* wb0 = wp0 + (hi * 256 + wv * 64 + ln32) * 8;
  const _Float16* wb1 = wp1 + (hi * 256 + wv * 64 + ln32) * 8;
  const _Float16* wb2 = wp2 + (hi * 256 + wv * 64 + ln32) * 8;
  const _Float16* wb3 = wp3 + (hi * 256 + wv * 64 + ln32) * 8;

  half8 gp0[8], gp1[8];   // pass-1 G prefetch (written in p==0, read in p==1)

#pragma unroll 1
  for (int p = 0; p < 2; ++p) {
    // per-n-tile row meta: row r = nt2*32+ln32, offset = 2p + (r>>6), q = r&63
    int pixr[4]; int eidx[4];
#pragma unroll
    for (int nt2 = 0; nt2 < 4; ++nt2) {
      int r = nt2 * 32 + ln32;
      int o = p * 2 + (r >> 6);
      int q = r & 63;
      pixr[nt2] = s_pix[o][q];
      eidx[nt2] = (o * 64 + q) * 8;              // halves into s_ext
    }

    // ---------------- layer 0: acc init from G + one ext K=16 step --------
    floatx16 acc[2][4];
    if (p == 0) {
#pragma unroll
      for (int mt2 = 0; mt2 < 2; ++mt2)
#pragma unroll
        for (int nt2 = 0; nt2 < 4; ++nt2) {
          const _Float16* ga = G + pixr[nt2] * 256 + (wv * 2 + mt2) * 32 + hi * 16;
          half8 g0 = *(const half8*)(ga);
          half8 g1 = *(const half8*)(ga + 8);
          floatx16 a;
#pragma unroll
          for (int j = 0; j < 8; ++j) {
            a[j]     = (float)g0[j];
            a[8 + j] = (float)g1[j];
          }
          acc[mt2][nt2] = a;
        }
    } else {
#pragma unroll
      for (int mt2 = 0; mt2 < 2; ++mt2)
#pragma unroll
        for (int nt2 = 0; nt2 < 4; ++nt2) {
          half8 g0 = gp0[mt2 * 4 + nt2];
          half8 g1 = gp1[mt2 * 4 + nt2];
          floatx16 a;
#pragma unroll
          for (int j = 0; j < 8; ++j) {
            a[j]     = (float)g0[j];
            a[8 + j] = (float)g1[j];
          }
          acc[mt2][nt2] = a;
        }
    }
    {   // ext step (kb 72+hi): W0 rows 576..591 (rows >= 584 are zero)
      half8 ae[2];
      ae[0] = *(const half8*)(wb0 + 36 * 4096);
      ae[1] = *(const half8*)(wb0 + 36 * 4096 + 256);
      half8 z = {(_Float16)0, (_Float16)0, (_Float16)0, (_Float16)0,
                 (_Float16)0, (_Float16)0, (_Float16)0, (_Float16)0};
      half8 bfe[4];
#pragma unroll
      for (int nt2 = 0; nt2 < 4; ++nt2)
        bfe[nt2] = (hi == 0) ? *(const half8*)(&s_ext[0][0][0] + eidx[nt2]) : z;
#pragma unroll
      for (int mt2 = 0; mt2 < 2; ++mt2)
#pragma unroll
        for (int nt2 = 0; nt2 < 4; ++nt2)
          acc[mt2][nt2] = __builtin_amdgcn_mfma_f32_32x32x16_f16(
              ae[mt2], bfe[nt2], acc[mt2][nt2], 0, 0, 0);
    }
    writeback32(acc, s_bias, s_h, wv, ln32, hi);  // prior L4 reads synced
    __syncthreads();

    // ---------------- layers 1..3: K = 256, ping-pong pipelined -----------
    layer256(wb1, s_h, ln32, hi, acc);
    __syncthreads();                // all reads of s_h done
    writeback32(acc, s_bias + 256, s_h, wv, ln32, hi);
    __syncthreads();

    layer256(wb2, s_h, ln32, hi, acc);
    __syncthreads();
    writeback32(acc, s_bias + 512, s_h, wv, ln32, hi);
    __syncthreads();

    layer256(wb3, s_h, ln32, hi, acc);
    __syncthreads();
    writeback32(acc, s_bias + 768, s_h, wv, ln32, hi);
    __syncthreads();

    // ---- T14: prefetch pass-1 G while L4+blend run (acc regs are dead) ----
    if (p == 0) {
#pragma unroll
      for (int nt2 = 0; nt2 < 4; ++nt2) {
        int r = nt2 * 32 + ln32;
        int o = 2 + (r >> 6);
        int q = r & 63;
        int pr = s_pix[o][q];
#pragma unroll
        for (int mt2 = 0; mt2 < 2; ++mt2) {
          const _Float16* ga = G + pr * 256 + (wv * 2 + mt2) * 32 + hi * 16;
          gp0[mt2 * 4 + nt2] = *(const half8*)(ga);
          gp1[mt2 * 4 + nt2] = *(const half8*)(ga + 8);
        }
      }
    }

    // ---------------- layer 4: 256 -> 3 (16x16x32, N padded 16) -----------
    half8 af4 = *(const half8*)(wp4 + (lg * 16 + ln16) * 8);  // s=0
    float4v a4[2];
    a4[0] = (float4v){0.f, 0.f, 0.f, 0.f};
    a4[1] = (float4v){0.f, 0.f, 0.f, 0.f};
#pragma unroll 1
    for (int s = 0; s < 8; ++s) {
      half8 afc = af4;
      if (s < 7)
        af4 = *(const half8*)(wp4 + (((s + 1) * 4 + lg) * 16 + ln16) * 8);
#pragma unroll
      for (int u = 0; u < 2; ++u) {
        int row = (2 * wv + u) * 16 + ln16;
        half8 bf = *(const half8*)(&s_h[row][s * 32 + lg * 8]);
        a4[u] = __builtin_amdgcn_mfma_f32_16x16x32_f16(afc, bf, a4[u], 0, 0, 0);
      }
    }
    if (lg == 0) {                   // lanes 0..15: out-ch j = reg j
#pragma unroll
      for (int u = 0; u < 2; ++u) {
        int row = (2 * wv + u) * 16 + ln16;
        *(float4v*)(&s_out[row][0]) = a4[u];
      }
    }
    __syncthreads();                 // s_out ready; s_h reads done

    if (t < 64) {                    // blend this pass's 2 offsets
      float a_lo = s_area[3 - 2 * p][t];      // rows 0-63:  o = 2p
      float a_hi = s_area[2 - 2 * p][t];      // rows 64-127: o = 2p+1
#pragma unroll
      for (int j = 0; j < 3; ++j)
        s_num[t][j] += s_out[t][j] * a_lo + s_out[64 + t][j] * a_hi;
    }
  }

  // ---- final: out = tanh(num/den + b4) * 1.01, f32 ----
  if (t < 64) {
    int q = q0 + t;
    if (q < NQ) {
      float den = s_area[0][t] + s_area[1][t] + s_area[2][t] + s_area[3][t];
      int ob = (bb * NQ + q) * 3;
#pragma unroll
      for (int j = 0; j < 3; ++j) {
        float v = s_num[t][j] / den + s_bias[1024 + j];
        out[ob + j] = tanhf(v) * 1.01f;
      }
    }
  }
}

// ---------------------------------------------------------------------------
extern "C" void kernel_launch(void* const* d_in, const int* in_sizes, int n_in,
                              void* d_out, int out_size, void* d_ws, size_t ws_size,
                              hipStream_t stream) {
  const float* inp   = (const float*)d_in[0];
  const float* coord = (const float*)d_in[1];
  const float* cell  = (const float*)d_in[2];
  const float* cw    = (const float*)d_in[3];
  const float* cb    = (const float*)d_in[4];
  const float* w0    = (const float*)d_in[5];
  const float* b0    = (const float*)d_in[6];
  const float* w1    = (const float*)d_in[7];
  const float* b1    = (const float*)d_in[8];
  const float* w2    = (const float*)d_in[9];
  const float* b2    = (const float*)d_in[10];
  const float* w3    = (const float*)d_in[11];
  const float* b3    = (const float*)d_in[12];
  const float* w4    = (const float*)d_in[13];
  const float* b4    = (const float*)d_in[14];

  char* ws = (char*)d_ws;
  _Float16* P   = (_Float16*)(ws);            // 2,458,624 B
  _Float16* wp0 = (_Float16*)(ws + 2458624);  //   303,104 B (74 kb)
  _Float16* wp1 = (_Float16*)(ws + 2761728);  //   131,072 B
  _Float16* wp2 = (_Float16*)(ws + 2892800);
  _Float16* wp3 = (_Float16*)(ws + 3023872);
  _Float16* wp4 = (_Float16*)(ws + 3154944);  //     8,192 B
  _Float16* G   = (_Float16*)(ws + 3163136);  // 9,834,496 B (2*98*98*256 f16)
  float* outp = (float*)d_out;

  hipLaunchKernelGGL(prep_conv_kernel, dim3(248), dim3(256), 0, stream,
                     w0, w1, w2, w3, w4, wp0, wp1, wp2, wp3, wp4,
                     inp, cw, cb, P);
  hipLaunchKernelGGL(gmat_kernel, dim3(384), dim3(256), 0, stream, P, wp0, G);
  hipLaunchKernelGGL(liif_main, dim3(8 * (QTP / 4)), dim3(256), 0, stream,
                     coord, cell, b0, b1, b2, b3, b4,
                     G, wp0, wp1, wp2, wp3, wp4, outp);
}

// Round 7
// 260.839 us; speedup vs baseline: 1.7269x; 1.2436x over previous
//
#include <hip/hip_runtime.h>

// ---------------------------------------------------------------------------
// LIIF forward, MI355X.  ALL tensors are float32 (per reference source).
// R23 = R22 MINUS the T14 G-prefetch (tripwire fired) = R20 liif verbatim +
// fused prep_conv + M-split gmat.
//   R22 post-mortem: prefetch spilled exactly as the tripwire predicted --
//   WRITE 0.7 -> 26.2MB, VGPR 112 -> 128 (cap), liif 184.8us.  The 16 half8
//   prefetch regs (64 VGPR) must be live ACROSS L4 (whose a4/bf regs + acc
//   writeback overlap them) -> allocator spilled the prefetch buffer itself;
//   each "prefetched" value became a scratch round-trip.  Lesson: at
//   (256,2)'s 128-reg cap, R16's liif has ~16 spare regs, not 64; any
//   cross-phase buffer >16 regs spills.
//   Final state: liif = R16 structure at its verified local optimum
//   (MfmaUtil 31.4% == MFMA-cycle/total ratio == arithmetic floor 42us /
//   134us; 5 structural escapes regressed with understood causes: R17 pass
//   quantum, R18 reg cap, R19 residency, R21 A-reuse, R22 reg pressure).
// Prediction: liif VGPR 112 / WRITE ~0.7MB / FETCH ~24MB / MfmaUtil ~31 /
// ~134us; total 258-266 (one fewer dispatch than R20's 267.0).  If >= 258
// with matching signature -> declare practical floor next round.
// R12 recap: G[pixel] = W0[0:576]^T unfold(pixel) in MFMA C-layout order
// (ch' = mt*32+hi*16+q*4+i <-> m = 8q+4hi+i); liif L0 = G gather (acc init)
// + one K=16 ext MFMA step; layers 1-3 32x32x16 ping-pong, packed cvt
// writeback, post-barrier weight loads.  absmax > 5.86e-3 => bug.
// ---------------------------------------------------------------------------

typedef _Float16 half8   __attribute__((ext_vector_type(8)));
typedef _Float16 half4v  __attribute__((ext_vector_type(4)));
typedef _Float16 half2v  __attribute__((ext_vector_type(2)));
typedef float    float4v __attribute__((ext_vector_type(4)));
typedef float    floatx16 __attribute__((ext_vector_type(16)));

// clamped f32->f16 (prep/conv side only)
__device__ __forceinline__ _Float16 to_h(float v) {
  return (_Float16)fminf(fmaxf(v, -60000.0f), 60000.0f);
}

#define NQ 30000
#define QT 469   // ceil(NQ/64) real tiles per batch
#define QTP 472  // padded to 4-multiple for XCD-partitioned grid (944 blocks)

// ---------------- fused weight repack + conv (R22) -------------------------
// blocks 0..75: conv 3x3 (3->64) + bias + tanh (19208 padded pixels)
// blocks 76..247: weight repack (idx < 44032), R14 layout:
//   wp: [kb][n][8] f16, element (n, k=kb*8+i) at ((kb*N + n)*8 + i).
__global__ void prep_conv_kernel(const float* __restrict__ w0,
                                 const float* __restrict__ w1,
                                 const float* __restrict__ w2,
                                 const float* __restrict__ w3,
                                 const float* __restrict__ w4,
                                 _Float16* __restrict__ p0, _Float16* __restrict__ p1,
                                 _Float16* __restrict__ p2, _Float16* __restrict__ p3,
                                 _Float16* __restrict__ p4,
                                 const float* __restrict__ inp,
                                 const float* __restrict__ cw,
                                 const float* __restrict__ cb,
                                 _Float16* __restrict__ P) {
  __shared__ __align__(16) float s_w[1728];
  __shared__ __align__(16) float s_b[64];
  if (blockIdx.x < 76) {
    // ---------------- conv part ----------------
    for (int i = threadIdx.x; i < 1728; i += 256) s_w[i] = cw[i];
    if (threadIdx.x < 64) s_b[threadIdx.x] = cb[threadIdx.x];
    __syncthreads();
    int tid = blockIdx.x * 256 + threadIdx.x;
    if (tid >= 2 * 98 * 98) return;
    int b = tid / 9604;
    int rem = tid % 9604;
    int yy = rem / 98, xx = rem % 98;
    alignas(16) _Float16 outv[64];
    if (yy == 0 || yy == 97 || xx == 0 || xx == 97) {
#pragma unroll
      for (int c = 0; c < 64; ++c) outv[c] = (_Float16)0.0f;
    } else {
      int y = yy - 1, x = xx - 1;
      float win[27];
#pragma unroll
      for (int ci = 0; ci < 3; ++ci)
#pragma unroll
        for (int ky = 0; ky < 3; ++ky)
#pragma unroll
          for (int kx = 0; kx < 3; ++kx) {
            int yi = y + ky - 1, xi = x + kx - 1;
            float v = 0.0f;
            if (yi >= 0 && yi < 96 && xi >= 0 && xi < 96)
              v = inp[((b * 3 + ci) * 96 + yi) * 96 + xi];
            win[ci * 9 + ky * 3 + kx] = v;
          }
      for (int co = 0; co < 64; ++co) {
        float acc = s_b[co];
#pragma unroll
        for (int k = 0; k < 27; ++k) acc = fmaf(win[k], s_w[co * 27 + k], acc);
        outv[co] = (_Float16)tanhf(acc);
      }
    }
    _Float16* dst = P + tid * 64;
#pragma unroll
    for (int j = 0; j < 8; ++j) ((half8*)dst)[j] = ((const half8*)outv)[j];
  } else {
    // ---------------- prep part ----------------
    int idx = (blockIdx.x - 76) * 256 + threadIdx.x;
    if (idx < 18944) {                       // wp0: (kb,n), kb 0..73
      int kb = idx >> 8, n = idx & 255;
      half8 hv;
#pragma unroll
      for (int i = 0; i < 8; ++i) {
        int f = kb * 8 + i;                  // permuted feature index
        float v = 0.0f;
        if (f < 576)      v = w0[((f & 63) * 9 + (f >> 6)) * 256 + n];
        else if (f < 580) v = w0[f * 256 + n];
        hv[i] = (_Float16)v;
      }
      *(half8*)(p0 + idx * 8) = hv;
    } else if (idx < 43520) {                // wp1..3: l*(32kb*256n)
      int j = idx - 18944;
      int l = j >> 13;                       // 8192 = 32*256 per layer
      int j2 = j & 8191;
      int kb = j2 >> 8, n = j2 & 255;
      const float* w = (l == 0) ? w1 : (l == 1) ? w2 : w3;
      _Float16* p = (l == 0) ? p1 : (l == 1) ? p2 : p3;
      half8 hv;
#pragma unroll
      for (int i = 0; i < 8; ++i)
        hv[i] = (_Float16)w[(kb * 8 + i) * 256 + n];
      *(half8*)(p + j2 * 8) = hv;
    } else if (idx < 44032) {                // wp4: 32kb * 16n
      int j = idx - 43520;
      int kb = j >> 4, n = j & 15;
      half8 hv;
#pragma unroll
      for (int i = 0; i < 8; ++i) {
        float v = (n < 3) ? w4[(kb * 8 + i) * 3 + n] : 0.0f;
        hv[i] = (_Float16)v;
      }
      *(half8*)(p4 + j * 8) = hv;
    }
  }
}

// ---------------- G precompute (R20: M-split, 384 blocks) ------------------
// G[pix] = W0[0:576]^T * unfold(pix).  1 WG = 1 window-base row x 1 M-half.
// Grid 384: bb = bit2 (same XCD rule as liif), mh = bit3, y = (blk>>4)*4 +
// (blk&3).  4 waves x 1 m-tile (32 ch) each: global m-tile = mh*4 + wv.
// LDS s_p[3][98][68]: pixel stride 68 halves = 34 dw = 2 mod 32 -> <=2-way
// bank conflicts (free).  acc[3]; store pre-permuted (R12 layout).
__global__ __launch_bounds__(256, 2) void gmat_kernel(
    const _Float16* __restrict__ P,
    const _Float16* __restrict__ wp0,
    _Float16* __restrict__ G) {
  __shared__ __align__(16) _Float16 s_p[3][98][68];

  const int t    = threadIdx.x;
  const int lane = t & 63;
  const int wv   = t >> 6;
  const int ln32 = lane & 31;
  const int hi   = lane >> 5;
  const int blk  = blockIdx.x;
  const int bb   = (blk & 4) >> 2;               // batch, matches liif XCD rule
  const int mh   = (blk >> 3) & 1;               // M half (128 ch)
  const int y    = (blk >> 4) * 4 + (blk & 3);   // window-base row 0..95
  const int mt   = mh * 4 + wv;                  // global m-tile 0..7

  // ---- stage P rows y..y+2 (3 x 98 pixels x 64 ch) coalesced ----
  const int rowbase = (bb * 98 + y) * 98 * 64;   // element idx of row y
  for (int j = t; j < 2352; j += 256) {          // 2352 = 3*98*8 chunks
    int row = j / 784;                           // 784 = 98*8
    int jr  = j - row * 784;
    half8 v = *(const half8*)(P + rowbase + row * 6272 + jr * 8);
    *(half8*)(&s_p[row][jr >> 3][(jr & 7) * 8]) = v;
  }
  __syncthreads();

  // weight base for this wave's m-tile: n = mt*32 + ln32
  const _Float16* wb0 = wp0 + (hi * 256 + mt * 32 + ln32) * 8;

  floatx16 acc[3];
#pragma unroll
  for (int nt = 0; nt < 3; ++nt) acc[nt] = (floatx16)(0.0f);

  half8 afA, afB;
  afA = *(const half8*)(wb0);
  afB = *(const half8*)(wb0 + 4096);

#pragma unroll 1
  for (int s = 0; s < 36; s += 2) {
    // step s (A)
    {
      const int patch = s >> 2;
      const int py = patch / 3, px = patch % 3;
      const int cb = ((s & 3) << 4) + hi * 8;
      half8 bf[3];
#pragma unroll
      for (int nt = 0; nt < 3; ++nt)
        bf[nt] = *(const half8*)(&s_p[py][nt * 32 + ln32 + px][cb]);
#pragma unroll
      for (int nt = 0; nt < 3; ++nt)
        acc[nt] = __builtin_amdgcn_mfma_f32_32x32x16_f16(afA, bf[nt], acc[nt], 0, 0, 0);
      const int sp = (s + 2 <= 35) ? (s + 2) : 35;   // weight prefetch
      afA = *(const half8*)(wb0 + sp * 4096);
    }
    // step s+1 (B)
    {
      const int s1 = s + 1;
      const int patch = s1 >> 2;
      const int py = patch / 3, px = patch % 3;
      const int cb = ((s1 & 3) << 4) + hi * 8;
      half8 bf[3];
#pragma unroll
      for (int nt = 0; nt < 3; ++nt)
        bf[nt] = *(const half8*)(&s_p[py][nt * 32 + ln32 + px][cb]);
#pragma unroll
      for (int nt = 0; nt < 3; ++nt)
        acc[nt] = __builtin_amdgcn_mfma_f32_32x32x16_f16(afB, bf[nt], acc[nt], 0, 0, 0);
      const int sp = (s + 3 <= 35) ? (s + 3) : 35;
      afB = *(const half8*)(wb0 + sp * 4096);
    }
  }
  // permuted store (RNE cvt): regs 0..15 already in ch' order q*4+i
  const int gybase = ((bb * 98 + y) * 98) * 256;
#pragma unroll
  for (int nt = 0; nt < 3; ++nt) {
    half8 c0, c1;
#pragma unroll
    for (int j = 0; j < 8; ++j) {
      c0[j] = (_Float16)acc[nt][j];
      c1[j] = (_Float16)acc[nt][8 + j];
    }
    _Float16* ga = G + gybase + (nt * 32 + ln32) * 256 + mt * 32 + hi * 16;
    *(half8*)(ga)     = c0;
    *(half8*)(ga + 8) = c1;
  }
}

// ---------------- main: gather + MLP + blend (R16 verbatim) ----------------
// WG = 256 thr = 4 waves = 64 queries x 2 offsets (128 rows) per pass.
// 32x32x16 C/D (measured m74/m101): n=lane&31, m=(reg&3)+8*(reg>>2)+4*(lane>>5).
__device__ __forceinline__ void writeback32(floatx16 (&acc)[2][4],
                                            const float* __restrict__ sb,
                                            _Float16 (*s_h)[264],
                                            int wv, int ln32, int hi) {
#pragma unroll
  for (int mt2 = 0; mt2 < 2; ++mt2) {
    const int mb = wv * 64 + mt2 * 32 + 4 * hi;
#pragma unroll
    for (int g = 0; g < 4; ++g) {
      const int m0 = mb + 8 * g;
      float b0 = sb[m0], b1 = sb[m0 + 1], b2 = sb[m0 + 2], b3 = sb[m0 + 3];
#pragma unroll
      for (int nt2 = 0; nt2 < 4; ++nt2) {
        const int n = nt2 * 32 + ln32;
        float v0 = fmaxf(acc[mt2][nt2][4 * g + 0] + b0, 0.0f);
        float v1 = fmaxf(acc[mt2][nt2][4 * g + 1] + b1, 0.0f);
        float v2 = fmaxf(acc[mt2][nt2][4 * g + 2] + b2, 0.0f);
        float v3 = fmaxf(acc[mt2][nt2][4 * g + 3] + b3, 0.0f);
        half2v lo  = __builtin_bit_cast(half2v, __builtin_amdgcn_cvt_pkrtz(v0, v1));
        half2v hi2 = __builtin_bit_cast(half2v, __builtin_amdgcn_cvt_pkrtz(v2, v3));
        half4v hv;
        hv[0] = lo[0]; hv[1] = lo[1]; hv[2] = hi2[0]; hv[3] = hi2[1];
        *(half4v*)(&s_h[n][m0]) = hv;
      }
    }
  }
}

// K=256 layer from s_h, ping-pong pipelined; loads after caller's barrier.
__device__ __forceinline__ void layer256(const _Float16* __restrict__ wbl,
                                         _Float16 (*s_h)[264],
                                         int ln32, int hi,
                                         floatx16 (&acc)[2][4]) {
#pragma unroll
  for (int mt2 = 0; mt2 < 2; ++mt2)
#pragma unroll
    for (int nt2 = 0; nt2 < 4; ++nt2) acc[mt2][nt2] = (floatx16)(0.0f);
  half8 afA[2], afB[2], bfA[4], bfB[4];
  afA[0] = *(const half8*)(wbl);
  afA[1] = *(const half8*)(wbl + 256);
  afB[0] = *(const half8*)(wbl + 4096);
  afB[1] = *(const half8*)(wbl + 4096 + 256);
#pragma unroll
  for (int nt2 = 0; nt2 < 4; ++nt2) {
    bfA[nt2] = *(const half8*)(&s_h[nt2 * 32 + ln32][hi * 8]);
    bfB[nt2] = *(const half8*)(&s_h[nt2 * 32 + ln32][16 + hi * 8]);
  }
#pragma unroll 1
  for (int s = 0; s < 16; s += 2) {
#pragma unroll
    for (int mt2 = 0; mt2 < 2; ++mt2)
#pragma unroll
      for (int nt2 = 0; nt2 < 4; ++nt2)
        acc[mt2][nt2] = __builtin_amdgcn_mfma_f32_32x32x16_f16(
            afA[mt2], bfA[nt2], acc[mt2][nt2], 0, 0, 0);
    {
      const int sc = (s + 2 < 16) ? (s + 2) : 0;
      const int sw = (s + 2 < 16) ? (s + 2) : 15;
      afA[0] = *(const half8*)(wbl + sw * 4096);
      afA[1] = *(const half8*)(wbl + sw * 4096 + 256);
#pragma unroll
      for (int nt2 = 0; nt2 < 4; ++nt2)
        bfA[nt2] = *(const half8*)(&s_h[nt2 * 32 + ln32][sc * 16 + hi * 8]);
    }
#pragma unroll
    for (int mt2 = 0; mt2 < 2; ++mt2)
#pragma unroll
      for (int nt2 = 0; nt2 < 4; ++nt2)
        acc[mt2][nt2] = __builtin_amdgcn_mfma_f32_32x32x16_f16(
            afB[mt2], bfB[nt2], acc[mt2][nt2], 0, 0, 0);
    {
      const int sc = (s + 3 < 16) ? (s + 3) : 0;
      const int sw = (s + 3 < 16) ? (s + 3) : 15;
      afB[0] = *(const half8*)(wbl + sw * 4096);
      afB[1] = *(const half8*)(wbl + sw * 4096 + 256);
#pragma unroll
      for (int nt2 = 0; nt2 < 4; ++nt2)
        bfB[nt2] = *(const half8*)(&s_h[nt2 * 32 + ln32][sc * 16 + hi * 8]);
    }
  }
}

__global__ __launch_bounds__(256, 2) void liif_main(
    const float* __restrict__ coord, const float* __restrict__ cell,
    const float* __restrict__ bias0, const float* __restrict__ bias1,
    const float* __restrict__ bias2, const float* __restrict__ bias3,
    const float* __restrict__ bias4,
    const _Float16* __restrict__ G,
    const _Float16* __restrict__ wp0, const _Float16* __restrict__ wp1,
    const _Float16* __restrict__ wp2, const _Float16* __restrict__ wp3,
    const _Float16* __restrict__ wp4,
    float* __restrict__ out) {
  __shared__ __align__(16) int      s_pix[4][64];
  __shared__ __align__(16) float    s_area[4][64];
  __shared__ __align__(16) _Float16 s_ext[4][64][8];
  __shared__ __align__(16) float    s_bias[1028];
  __shared__ __align__(16) float    s_out[128][4];
  __shared__ __align__(16) float    s_num[64][4];
  __shared__ __align__(16) _Float16 s_h[128][264]; // stride 132 dw = 4 mod 32

  const int t   = threadIdx.x;
  const int blk = blockIdx.x;
  const int bb  = (blk & 4) >> 2;            // batch = bit2 -> stable per XCD
  const int tile = (blk >> 3) * 4 + (blk & 3);
  const int q0  = tile * 64;

  // ---- stage biases into LDS (1027 f32) ----
  for (int i = t; i < 1027; i += 256) {
    float v;
    if (i < 256)       v = bias0[i];
    else if (i < 512)  v = bias1[i - 256];
    else if (i < 768)  v = bias2[i - 512];
    else if (i < 1024) v = bias3[i - 768];
    else               v = bias4[i - 1024];
    s_bias[i] = v;
  }

  // ---- phase 0: per-row meta for all 4 offsets (f32, matches np) ----
  if (t < 64) {
    int q = q0 + t;
    bool valid = q < NQ;
    float c0 = 0.f, c1 = 0.f, e0 = 0.f, e1 = 0.f;
    if (valid) {
      int base = (bb * NQ + q) * 2;
      c0 = coord[base]; c1 = coord[base + 1];
      e0 = cell[base];  e1 = cell[base + 1];
    }
    float rc0 = e0 * 96.0f, rc1 = e1 * 96.0f;
#pragma unroll
    for (int o = 0; o < 4; ++o) {
      float oy = (o < 2) ? -1.0f : 1.0f;     // offsets [-1,-1],[-1,1],[1,-1],[1,1]
      float ox = (o & 1) ? 1.0f : -1.0f;
      float ec0 = (c0 + oy * (1.0f / 96.0f)) + 1e-6f;
      float ec1 = (c1 + ox * (1.0f / 96.0f)) + 1e-6f;
      ec0 = fminf(fmaxf(ec0, -1.0f), 1.0f);  // f32(-1+1e-10) == -1.0f
      ec1 = fminf(fmaxf(ec1, -1.0f), 1.0f);
      int iy = (int)rintf(((ec0 + 1.0f) * 96.0f) * 0.5f - 0.5f);  // half-even
      int ix = (int)rintf(((ec1 + 1.0f) * 96.0f) * 0.5f - 0.5f);
      iy = min(max(iy, 0), 95); ix = min(max(ix, 0), 95);
      float qc0 = -1.0f + (2.0f * (float)iy + 1.0f) / 96.0f;
      float qc1 = -1.0f + (2.0f * (float)ix + 1.0f) / 96.0f;
      float r0 = (c0 - qc0) * 96.0f;
      float r1 = (c1 - qc1) * 96.0f;
      s_pix[o][t]  = (bb * 98 + iy) * 98 + ix;   // padded pixel base
      s_area[o][t] = fabsf(r0 * r1) + 1e-9f;
      s_ext[o][t][0] = to_h(r0);  s_ext[o][t][1] = to_h(r1);
      s_ext[o][t][2] = to_h(rc0); s_ext[o][t][3] = to_h(rc1);
      s_ext[o][t][4] = (_Float16)0.0f; s_ext[o][t][5] = (_Float16)0.0f;
      s_ext[o][t][6] = (_Float16)0.0f; s_ext[o][t][7] = (_Float16)0.0f;
    }
    s_num[t][0] = 0.f; s_num[t][1] = 0.f; s_num[t][2] = 0.f; s_num[t][3] = 0.f;
  }
  __syncthreads();

  const int lane = t & 63;
  const int wv   = t >> 6;
  const int ln32 = lane & 31;
  const int hi   = lane >> 5;
  const int ln16 = lane & 15;
  const int lg   = lane >> 4;

  const _Float16* wb0 = wp0 + (hi * 256 + wv * 64 + ln32) * 8;
  const _Float16* wb1 = wp1 + (hi * 256 + wv * 64 + ln32) * 8;
  const _Float16* wb2 = wp2 + (hi * 256 + wv * 64 + ln32) * 8;
  const _Float16* wb3 = wp3 + (hi * 256 + wv * 64 + ln32) * 8;

#pragma unroll 1
  for (int p = 0; p < 2; ++p) {
    // per-n-tile row meta: row r = nt2*32+ln32, offset = 2p + (r>>6), q = r&63
    int pixr[4]; int eidx[4];
#pragma unroll
    for (int nt2 = 0; nt2 < 4; ++nt2) {
      int r = nt2 * 32 + ln32;
      int o = p * 2 + (r >> 6);
      int q = r & 63;
      pixr[nt2] = s_pix[o][q];
      eidx[nt2] = (o * 64 + q) * 8;              // halves into s_ext
    }

    // ---------------- layer 0: acc init from G + one ext K=16 step --------
    floatx16 acc[2][4];
#pragma unroll
    for (int mt2 = 0; mt2 < 2; ++mt2)
#pragma unroll
      for (int nt2 = 0; nt2 < 4; ++nt2) {
        const _Float16* ga = G + pixr[nt2] * 256 + (wv * 2 + mt2) * 32 + hi * 16;
        half8 g0 = *(const half8*)(ga);
        half8 g1 = *(const half8*)(ga + 8);
        floatx16 a;
#pragma unroll
        for (int j = 0; j < 8; ++j) {
          a[j]     = (float)g0[j];
          a[8 + j] = (float)g1[j];
        }
        acc[mt2][nt2] = a;
      }
    {   // ext step (kb 72+hi): W0 rows 576..591 (rows >= 584 are zero)
      half8 ae[2];
      ae[0] = *(const half8*)(wb0 + 36 * 4096);
      ae[1] = *(const half8*)(wb0 + 36 * 4096 + 256);
      half8 z = {(_Float16)0, (_Float16)0, (_Float16)0, (_Float16)0,
                 (_Float16)0, (_Float16)0, (_Float16)0, (_Float16)0};
      half8 bfe[4];
#pragma unroll
      for (int nt2 = 0; nt2 < 4; ++nt2)
        bfe[nt2] = (hi == 0) ? *(const half8*)(&s_ext[0][0][0] + eidx[nt2]) : z;
#pragma unroll
      for (int mt2 = 0; mt2 < 2; ++mt2)
#pragma unroll
        for (int nt2 = 0; nt2 < 4; ++nt2)
          acc[mt2][nt2] = __builtin_amdgcn_mfma_f32_32x32x16_f16(
              ae[mt2], bfe[nt2], acc[mt2][nt2], 0, 0, 0);
    }
    writeback32(acc, s_bias, s_h, wv, ln32, hi);  // prior L4 reads synced
    __syncthreads();

    // ---------------- layers 1..3: K = 256, ping-pong pipelined -----------
    layer256(wb1, s_h, ln32, hi, acc);
    __syncthreads();                // all reads of s_h done
    writeback32(acc, s_bias + 256, s_h, wv, ln32, hi);
    __syncthreads();

    layer256(wb2, s_h, ln32, hi, acc);
    __syncthreads();
    writeback32(acc, s_bias + 512, s_h, wv, ln32, hi);
    __syncthreads();

    layer256(wb3, s_h, ln32, hi, acc);
    __syncthreads();
    writeback32(acc, s_bias + 768, s_h, wv, ln32, hi);
    __syncthreads();

    // ---------------- layer 4: 256 -> 3 (16x16x32, N padded 16) -----------
    half8 af4 = *(const half8*)(wp4 + (lg * 16 + ln16) * 8);  // s=0
    float4v a4[2];
    a4[0] = (float4v){0.f, 0.f, 0.f, 0.f};
    a4[1] = (float4v){0.f, 0.f, 0.f, 0.f};
#pragma unroll 1
    for (int s = 0; s < 8; ++s) {
      half8 afc = af4;
      if (s < 7)
        af4 = *(const half8*)(wp4 + (((s + 1) * 4 + lg) * 16 + ln16) * 8);
#pragma unroll
      for (int u = 0; u < 2; ++u) {
        int row = (2 * wv + u) * 16 + ln16;
        half8 bf = *(const half8*)(&s_h[row][s * 32 + lg * 8]);
        a4[u] = __builtin_amdgcn_mfma_f32_16x16x32_f16(afc, bf, a4[u], 0, 0, 0);
      }
    }
    if (lg == 0) {                   // lanes 0..15: out-ch j = reg j
#pragma unroll
      for (int u = 0; u < 2; ++u) {
        int row = (2 * wv + u) * 16 + ln16;
        *(float4v*)(&s_out[row][0]) = a4[u];
      }
    }
    __syncthreads();                 // s_out ready; s_h reads done

    if (t < 64) {                    // blend this pass's 2 offsets
      float a_lo = s_area[3 - 2 * p][t];      // rows 0-63:  o = 2p
      float a_hi = s_area[2 - 2 * p][t];      // rows 64-127: o = 2p+1
#pragma unroll
      for (int j = 0; j < 3; ++j)
        s_num[t][j] += s_out[t][j] * a_lo + s_out[64 + t][j] * a_hi;
    }
  }

  // ---- final: out = tanh(num/den + b4) * 1.01, f32 ----
  if (t < 64) {
    int q = q0 + t;
    if (q < NQ) {
      float den = s_area[0][t] + s_area[1][t] + s_area[2][t] + s_area[3][t];
      int ob = (bb * NQ + q) * 3;
#pragma unroll
      for (int j = 0; j < 3; ++j) {
        float v = s_num[t][j] / den + s_bias[1024 + j];
        out[ob + j] = tanhf(v) * 1.01f;
      }
    }
  }
}

// ---------------------------------------------------------------------------
extern "C" void kernel_launch(void* const* d_in, const int* in_sizes, int n_in,
                              void* d_out, int out_size, void* d_ws, size_t ws_size,
                              hipStream_t stream) {
  const float* inp   = (const float*)d_in[0];
  const float* coord = (const float*)d_in[1];
  const float* cell  = (const float*)d_in[2];
  const float* cw    = (const float*)d_in[3];
  const float* cb    = (const float*)d_in[4];
  const float* w0    = (const float*)d_in[5];
  const float* b0    = (const float*)d_in[6];
  const float* w1    = (const float*)d_in[7];
  const float* b1    = (const float*)d_in[8];
  const float* w2    = (const float*)d_in[9];
  const float* b2    = (const float*)d_in[10];
  const float* w3    = (const float*)d_in[11];
  const float* b3    = (const float*)d_in[12];
  const float* w4    = (const float*)d_in[13];
  const float* b4    = (const float*)d_in[14];

  char* ws = (char*)d_ws;
  _Float16* P   = (_Float16*)(ws);            // 2,458,624 B
  _Float16* wp0 = (_Float16*)(ws + 2458624);  //   303,104 B (74 kb)
  _Float16* wp1 = (_Float16*)(ws + 2761728);  //   131,072 B
  _Float16* wp2 = (_Float16*)(ws + 2892800);
  _Float16* wp3 = (_Float16*)(ws + 3023872);
  _Float16* wp4 = (_Float16*)(ws + 3154944);  //     8,192 B
  _Float16* G   = (_Float16*)(ws + 3163136);  // 9,834,496 B (2*98*98*256 f16)
  float* outp = (float*)d_out;

  hipLaunchKernelGGL(prep_conv_kernel, dim3(248), dim3(256), 0, stream,
                     w0, w1, w2, w3, w4, wp0, wp1, wp2, wp3, wp4,
                     inp, cw, cb, P);
  hipLaunchKernelGGL(gmat_kernel, dim3(384), dim3(256), 0, stream, P, wp0, G);
  hipLaunchKernelGGL(liif_main, dim3(8 * (QTP / 4)), dim3(256), 0, stream,
                     coord, cell, b0, b1, b2, b3, b4,
                     G, wp0, wp1, wp2, wp3, wp4, outp);
}